// Round 19
// baseline (117.457 us; speedup 1.0000x reference)
//
#include <hip/hip_runtime.h>
#include <hip/hip_bf16.h>

#define BSZ  131072
#define DIM  256
#define ROWS 32                    // rows per tile
#define NT   1024                  // 16 waves; wave w owns output cols [w*16, w*16+16)
#define NBLK 512                   // 2 blocks/CU (two independent barrier domains)
#define TPB  (BSZ / ROWS / NBLK)   // 8 tiles per block

typedef __attribute__((ext_vector_type(4))) float f32x4;
typedef __attribute__((ext_vector_type(2))) unsigned int u32x2;

// LDS map (50176 B -> 2 blocks/CU):
//  zbuf[2] : [32 rows][256 fp8 + 8B pad] stride 264 -> 8448 each @ 0, 8448
//  obuf    : [32 rows][256 f32 + 16B pad] stride 1040 -> 33280 @ 16896
#define ZSTR  264
#define OSTR  1040
#define ZBB(b) ((b) * 8448)
#define OBASE 16896

// HW packed f32->fp8(e4m3) conversion: 2 instrs per 4 floats.
__device__ __forceinline__ unsigned pk4(f32x4 v) {
  unsigned r;
  asm("v_cvt_pk_fp8_f32 %0, %1, %2" : "=v"(r) : "v"(v[0]), "v"(v[1]));
  asm("v_cvt_pk_fp8_f32 %0, %1, %2 op_sel:[0,0,1]" : "+v"(r) : "v"(v[2]), "v"(v[3]));
  return r;
}

// ---------------- prep: f32 W -> fp8 wT8, K-major: wT8[kb][j][32] (bytes) ----------------
__global__ void prep_kernel(const float* __restrict__ Wmu, const float* __restrict__ Wsd,
                            unsigned char* __restrict__ wm, unsigned char* __restrict__ wsd) {
  const int tg = blockIdx.x * 256 + threadIdx.x;   // 16384 threads
  const int j  = tg >> 6, kq = tg & 63;            // row j, k-quad (k0 = kq*4)
  const int dst = ((kq >> 3) << 13) + (j << 5) + ((kq & 7) << 2);  // byte offset
  f32x4 a = *(const f32x4*)(Wmu + j * 256 + kq * 4);
  f32x4 b = *(const f32x4*)(Wsd + j * 256 + kq * 4);
  *(unsigned*)(wm + dst)  = pk4(a);
  *(unsigned*)(wsd + dst) = pk4(b);
}

// ---------------- main: fp8 MFMA, W in regs, 2 barrier domains/CU ----------------
__global__ __launch_bounds__(NT, 8)
void main_kernel(const float* __restrict__ z,
                 const unsigned char* __restrict__ wm8,
                 const unsigned char* __restrict__ ws8,
                 const float* __restrict__ bmu,
                 const float* __restrict__ bsd,
                 float* __restrict__ out,
                 float* __restrict__ partials) {
  __shared__ unsigned char smem[50176];
  __shared__ float redbuf[16];
  const int t = threadIdx.x, lane = t & 63, w = t >> 6;   // w 0..15
  const int bid = blockIdx.x;

  // ---- W fragments in regs: wave w -> cols [w*16, w*16+16), both matrices (32 VGPRs) ----
  const int jrow = w * 16 + (lane & 15);
  long wfm[8], wfs[8];
#pragma unroll
  for (int kb = 0; kb < 8; ++kb) {
    const int a = (kb << 13) + jrow * 32 + ((lane >> 4) << 3);
    wfm[kb] = *(const long*)(wm8 + a);
    wfs[kb] = *(const long*)(ws8 + a);
  }
  const int colb = w * 16 + ((lane >> 4) << 2);
  const f32x4 b4m = *(const f32x4*)(bmu + colb);
  const f32x4 b4s = *(const f32x4*)(bsd + colb);

  // ---- per-thread addressing ----
  const int zrow = t >> 5, zc = t & 31;                       // stage: 8 f32 -> 8 fp8
  const int zwofs = zrow * ZSTR + zc * 8;
  const int zro   = (lane & 15) * ZSTR + ((lane >> 4) << 3);  // + nj*16*ZSTR + kb*32
  const int ow    = (lane & 15) * OSTR + colb * 4;            // + nj*16*OSTR

  const size_t TSTEP = (size_t)NBLK * ROWS * DIM;             // elems between my tiles
  const float* zp = z + (size_t)(bid * ROWS + zrow) * DIM + zc * 8;
  float* op = out + (size_t)(bid * ROWS) * DIM;

  float klp = 0.0f;
  f32x4 pza, pzb;

  // ---- prologue: stage z(0) into buf0; prefetch z(1) into regs ----
  {
    f32x4 a = *(const f32x4*)zp;
    f32x4 b = *(const f32x4*)(zp + 4);
    u32x2 p; p[0] = pk4(a); p[1] = pk4(b);
    *(u32x2*)(smem + ZBB(0) + zwofs) = p;
  }
  pza = *(const f32x4*)(zp + TSTEP);
  pzb = *(const f32x4*)(zp + TSTEP + 4);
  asm volatile("s_waitcnt lgkmcnt(0)" ::: "memory");
  __builtin_amdgcn_sched_barrier(0);
  __builtin_amdgcn_s_barrier();

  // ---- tile loop: P1{A,B,C,D} E1 | P2{F} E2 ----
#pragma unroll 1
  for (int i = 0; i < TPB; ++i) {
    // A: stage z(i+1) into zbuf[(i+1)&1] (readers C(i-1) retired at E1(i-1))
    if (i < TPB - 1) {
      u32x2 p; p[0] = pk4(pza); p[1] = pk4(pzb);
      *(u32x2*)(smem + ZBB((i + 1) & 1) + zwofs) = p;
    }
    // B: prefetch z(i+2) (stays in flight across barriers)
    if (i < TPB - 2) {
      pza = *(const f32x4*)(zp + (size_t)(i + 2) * TSTEP);
      pzb = *(const f32x4*)(zp + (size_t)(i + 2) * TSTEP + 4);
    }

    // C: compute tile i from zbuf[i&1]
    const unsigned char* zb = smem + ZBB(i & 1);
    f32x4 am[2], al[2];
    am[0] = (f32x4)0.0f; am[1] = (f32x4)0.0f;
    al[0] = (f32x4)0.0f; al[1] = (f32x4)0.0f;
#pragma unroll
    for (int kb = 0; kb < 8; ++kb)
#pragma unroll
      for (int nj = 0; nj < 2; ++nj) {
        const long zf = *(const long*)(zb + nj * 16 * ZSTR + (kb << 5) + zro);
        am[nj] = __builtin_amdgcn_mfma_f32_16x16x32_fp8_fp8(wfm[kb], zf, am[nj], 0, 0, 0);
        al[nj] = __builtin_amdgcn_mfma_f32_16x16x32_fp8_fp8(wfs[kb], zf, al[nj], 0, 0, 0);
      }

    // D: epilogue -> obuf (F(i-1)'s reads drained at E2(i-1))
#pragma unroll
    for (int nj = 0; nj < 2; ++nj) {
      f32x4 mu4;
#pragma unroll
      for (int r = 0; r < 4; ++r) {
        float mu = fmaxf(am[nj][r] + b4m[r], 0.0f);
        float ls = fmaxf(al[nj][r] + b4s[r], 0.0f);
        float iv = __expf(-2.0f * ls);
        klp += fmaf(2.0f, ls, fmaf(mu * mu, iv, iv));   // (1+mu^2)*iv + 2*ls; -1 folded at end
        mu4[r] = mu;
      }
      *(f32x4*)(smem + OBASE + nj * 16 * OSTR + ow) = mu4;
    }

    // E1: A+D writes visible; C reads retired
    asm volatile("s_waitcnt lgkmcnt(0)" ::: "memory");
    __builtin_amdgcn_sched_barrier(0);
    __builtin_amdgcn_s_barrier();

    // F: coalesced NT stores (wave stores rows 2w, 2w+1; 1KB contiguous each)
#pragma unroll
    for (int rr = 0; rr < 2; ++rr) {
      const int row = w * 2 + rr;
      const f32x4 v = *(const f32x4*)(smem + OBASE + row * OSTR + lane * 16);
      __builtin_nontemporal_store(v, (f32x4*)(op + (size_t)i * TSTEP + row * DIM + lane * 4));
    }

    // E2: F's obuf reads retired -> D(i+1) may overwrite
    asm volatile("s_waitcnt lgkmcnt(0)" ::: "memory");
    __builtin_amdgcn_sched_barrier(0);
    __builtin_amdgcn_s_barrier();
  }

  // ---- KL reduction ----
  klp = 0.5f * (klp - (float)(TPB * 8));   // 64 elems per lane, each owes -1
#pragma unroll
  for (int off = 32; off; off >>= 1) klp += __shfl_down(klp, off);
  if (lane == 0) redbuf[w] = klp;
  __syncthreads();
  if (t == 0) {
    float s = 0.0f;
#pragma unroll
    for (int i = 0; i < 16; ++i) s += redbuf[i];
    partials[bid] = s;
  }
}

// ---------------- finalize ----------------
__global__ void fin_kernel(const float* __restrict__ partials, float* __restrict__ out) {
  __shared__ double red[256];
  red[threadIdx.x] = (double)partials[threadIdx.x] + (double)partials[threadIdx.x + 256];
  __syncthreads();
  for (int st = 128; st > 0; st >>= 1) {
    if ((int)threadIdx.x < st) red[threadIdx.x] += red[threadIdx.x + st];
    __syncthreads();
  }
  if (threadIdx.x == 0) out[(size_t)BSZ * DIM] = (float)(red[0] / (double)BSZ);
}

// ---------------- launch ----------------
// ws: [0,16384) float partials[512](+pad); [16384,+64K) wT8_mu; [81920,+64K) wT8_sd.
// Total 147456 B.
extern "C" void kernel_launch(void* const* d_in, const int* in_sizes, int n_in,
                              void* d_out, int out_size, void* d_ws, size_t ws_size,
                              hipStream_t stream) {
  const float* z   = (const float*)d_in[0];
  const float* Wmu = (const float*)d_in[1];
  const float* bmu = (const float*)d_in[2];
  const float* Wsd = (const float*)d_in[3];
  const float* bsd = (const float*)d_in[4];
  float* out = (float*)d_out;

  float* partials    = (float*)d_ws;
  unsigned char* wm8 = (unsigned char*)d_ws + 16384;
  unsigned char* ws8 = wm8 + DIM * DIM;

  prep_kernel<<<64, 256, 0, stream>>>(Wmu, Wsd, wm8, ws8);
  main_kernel<<<NBLK, NT, 0, stream>>>(z, wm8, ws8, bmu, bsd, out, partials);
  fin_kernel<<<1, 256, 0, stream>>>(partials, out);
}

// Round 20
// 53.645 us; speedup vs baseline: 2.1895x; 2.1895x over previous
//
#include <hip/hip_runtime.h>
#include <hip/hip_bf16.h>

#define BSZ  131072
#define DIM  256
#define ROWS 32                    // rows per tile
#define NT   1024                  // 16 waves; wave w owns output cols [w*16, w*16+16)
#define NBLK 256                   // persistent: 1 block/CU
#define TPB  (BSZ / ROWS / NBLK)   // 16 tiles per block

typedef __attribute__((ext_vector_type(4))) float f32x4;
typedef __attribute__((ext_vector_type(2))) unsigned int u32x2;

// LDS map (83456 B, 1 block/CU):
//  zbuf[2] : [32 rows][256 fp8 + 8B pad] stride 264 -> 8448 each @ 0, 8448
//  obuf[2] : [32 rows][256 f32 + 16B pad] stride 1040 -> 33280 each @ 16896, 50176
#define ZSTR  264
#define OSTR  1040
#define ZBB(b) ((b) * 8448)
#define OB(b)  (16896 + (b) * 33280)

// HW packed f32->fp8(e4m3) conversion: 2 instrs per 4 floats.
__device__ __forceinline__ unsigned pk4(f32x4 v) {
  unsigned r;
  asm("v_cvt_pk_fp8_f32 %0, %1, %2" : "=v"(r) : "v"(v[0]), "v"(v[1]));
  asm("v_cvt_pk_fp8_f32 %0, %1, %2 op_sel:[0,0,1]" : "+v"(r) : "v"(v[2]), "v"(v[3]));
  return r;
}

// ---------------- prep: f32 W -> fp8 wT8, K-major: wT8[kb][j][32] (bytes) ----------------
__global__ void prep_kernel(const float* __restrict__ Wmu, const float* __restrict__ Wsd,
                            unsigned char* __restrict__ wm, unsigned char* __restrict__ wsd) {
  const int tg = blockIdx.x * 256 + threadIdx.x;   // 16384 threads
  const int j  = tg >> 6, kq = tg & 63;            // row j, k-quad (k0 = kq*4)
  const int dst = ((kq >> 3) << 13) + (j << 5) + ((kq & 7) << 2);  // byte offset
  f32x4 a = *(const f32x4*)(Wmu + j * 256 + kq * 4);
  f32x4 b = *(const f32x4*)(Wsd + j * 256 + kq * 4);
  *(unsigned*)(wm + dst)  = pk4(a);
  *(unsigned*)(wsd + dst) = pk4(b);
}

// ---------------- main: persistent, fp8 MFMA, W in regs (16 cols/wave) ----------------
__global__ __launch_bounds__(NT, 4)
void main_kernel(const float* __restrict__ z,
                 const unsigned char* __restrict__ wm8,
                 const unsigned char* __restrict__ ws8,
                 const float* __restrict__ bmu,
                 const float* __restrict__ bsd,
                 float* __restrict__ out,
                 float* __restrict__ partials) {
  __shared__ unsigned char smem[83456];
  __shared__ float redbuf[16];
  const int t = threadIdx.x, lane = t & 63, w = t >> 6;   // w 0..15
  const int bid = blockIdx.x;

  // ---- W fragments in regs: wave w -> cols [w*16, w*16+16), both matrices ----
  const int jrow = w * 16 + (lane & 15);
  long wfm[8], wfs[8];
#pragma unroll
  for (int kb = 0; kb < 8; ++kb) {
    const int a = (kb << 13) + jrow * 32 + ((lane >> 4) << 3);
    wfm[kb] = *(const long*)(wm8 + a);
    wfs[kb] = *(const long*)(ws8 + a);
  }
  const int colb = w * 16 + ((lane >> 4) << 2);
  const f32x4 b4m = *(const f32x4*)(bmu + colb);
  const f32x4 b4s = *(const f32x4*)(bsd + colb);

  // ---- per-thread addressing ----
  const int zrow = t >> 5, zc = t & 31;                       // stage: 8 f32 -> 8 fp8
  const int zwofs = zrow * ZSTR + zc * 8;
  const int zro   = (lane & 15) * ZSTR + ((lane >> 4) << 3);  // + nj*16*ZSTR + kb*32
  const int ow    = (lane & 15) * OSTR + colb * 4;            // + nj*16*OSTR

  const size_t TSTEP = (size_t)NBLK * ROWS * DIM;             // elems between my tiles
  const float* zp = z + (size_t)(bid * ROWS + zrow) * DIM + zc * 8;
  float* op = out + (size_t)(bid * ROWS) * DIM;

  float klp = 0.0f;
  f32x4 pza, pzb;

  // ---- prologue: stage z(0) into buf0; prefetch z(1) into regs ----
  {
    f32x4 a = *(const f32x4*)zp;
    f32x4 b = *(const f32x4*)(zp + 4);
    u32x2 p; p[0] = pk4(a); p[1] = pk4(b);
    *(u32x2*)(smem + ZBB(0) + zwofs) = p;
  }
  pza = *(const f32x4*)(zp + TSTEP);
  pzb = *(const f32x4*)(zp + TSTEP + 4);
  asm volatile("s_waitcnt lgkmcnt(0)" ::: "memory");
  __builtin_amdgcn_sched_barrier(0);
  __builtin_amdgcn_s_barrier();

  // ---- tile loop: ONE barrier per tile ----
#pragma unroll 1
  for (int i = 0; i < TPB; ++i) {
    // A: stage z(i+1) into zbuf[(i+1)&1] (readers finished at barrier(i-1))
    if (i < TPB - 1) {
      u32x2 p; p[0] = pk4(pza); p[1] = pk4(pzb);
      *(u32x2*)(smem + ZBB((i + 1) & 1) + zwofs) = p;
    }
    // B: prefetch z(i+2) (in flight across the barrier)
    if (i < TPB - 2) {
      pza = *(const f32x4*)(zp + (size_t)(i + 2) * TSTEP);
      pzb = *(const f32x4*)(zp + (size_t)(i + 2) * TSTEP + 4);
    }

    // C: compute tile i from zbuf[i&1]
    const unsigned char* zb = smem + ZBB(i & 1);
    f32x4 am[2], al[2];
    am[0] = (f32x4)0.0f; am[1] = (f32x4)0.0f;
    al[0] = (f32x4)0.0f; al[1] = (f32x4)0.0f;
#pragma unroll
    for (int kb = 0; kb < 8; ++kb)
#pragma unroll
      for (int nj = 0; nj < 2; ++nj) {
        const long zf = *(const long*)(zb + nj * 16 * ZSTR + (kb << 5) + zro);
        am[nj] = __builtin_amdgcn_mfma_f32_16x16x32_fp8_fp8(wfm[kb], zf, am[nj], 0, 0, 0);
        al[nj] = __builtin_amdgcn_mfma_f32_16x16x32_fp8_fp8(wfs[kb], zf, al[nj], 0, 0, 0);
      }

    // D: epilogue -> obuf[i&1]
#pragma unroll
    for (int nj = 0; nj < 2; ++nj) {
      f32x4 mu4;
#pragma unroll
      for (int r = 0; r < 4; ++r) {
        float mu = fmaxf(am[nj][r] + b4m[r], 0.0f);
        float ls = fmaxf(al[nj][r] + b4s[r], 0.0f);
        float iv = __expf(-2.0f * ls);
        klp += fmaf(2.0f, ls, fmaf(mu * mu, iv, iv));   // (1+mu^2)*iv + 2*ls; -1 folded at end
        mu4[r] = mu;
      }
      *(f32x4*)(smem + OB(i & 1) + nj * 16 * OSTR + ow) = mu4;
    }

    // E: the single barrier
    asm volatile("s_waitcnt lgkmcnt(0)" ::: "memory");
    __builtin_amdgcn_sched_barrier(0);
    __builtin_amdgcn_s_barrier();

    // F: coalesced NT stores of tile i (wave stores rows 2w, 2w+1; 1KB contiguous each)
#pragma unroll
    for (int rr = 0; rr < 2; ++rr) {
      const int row = w * 2 + rr;
      const f32x4 v = *(const f32x4*)(smem + OB(i & 1) + row * OSTR + lane * 16);
      __builtin_nontemporal_store(v, (f32x4*)(op + (size_t)i * TSTEP + row * DIM + lane * 4));
    }
  }

  // ---- KL reduction ----
  klp = 0.5f * (klp - (float)(TPB * 8));   // 128 elems per lane, each owes -1
#pragma unroll
  for (int off = 32; off; off >>= 1) klp += __shfl_down(klp, off);
  if (lane == 0) redbuf[w] = klp;
  __syncthreads();
  if (t == 0) {
    float s = 0.0f;
#pragma unroll
    for (int i = 0; i < 16; ++i) s += redbuf[i];
    partials[bid] = s;
  }
}

// ---------------- finalize ----------------
__global__ void fin_kernel(const float* __restrict__ partials, float* __restrict__ out) {
  __shared__ double red[256];
  red[threadIdx.x] = (double)partials[threadIdx.x];
  __syncthreads();
  for (int st = 128; st > 0; st >>= 1) {
    if ((int)threadIdx.x < st) red[threadIdx.x] += red[threadIdx.x + st];
    __syncthreads();
  }
  if (threadIdx.x == 0) out[(size_t)BSZ * DIM] = (float)(red[0] / (double)BSZ);
}

// ---------------- launch ----------------
// ws: [0,16384) float partials[256](+pad); [16384,+64K) wT8_mu; [81920,+64K) wT8_sd.
// Total 147456 B.
extern "C" void kernel_launch(void* const* d_in, const int* in_sizes, int n_in,
                              void* d_out, int out_size, void* d_ws, size_t ws_size,
                              hipStream_t stream) {
  const float* z   = (const float*)d_in[0];
  const float* Wmu = (const float*)d_in[1];
  const float* bmu = (const float*)d_in[2];
  const float* Wsd = (const float*)d_in[3];
  const float* bsd = (const float*)d_in[4];
  float* out = (float*)d_out;

  float* partials    = (float*)d_ws;
  unsigned char* wm8 = (unsigned char*)d_ws + 16384;
  unsigned char* ws8 = wm8 + DIM * DIM;

  prep_kernel<<<64, 256, 0, stream>>>(Wmu, Wsd, wm8, ws8);
  main_kernel<<<NBLK, NT, 0, stream>>>(z, wm8, ws8, bmu, bsd, out, partials);
  fin_kernel<<<1, 256, 0, stream>>>(partials, out);
}